// Round 4
// baseline (652.837 us; speedup 1.0000x reference)
//
#include <hip/hip_runtime.h>
#include <hip/hip_bf16.h>

typedef __hip_bfloat16 bf16;
typedef __bf16 bf16x8 __attribute__((ext_vector_type(8)));
typedef float f32x4 __attribute__((ext_vector_type(4)));

#define B_ 4
#define S_ 4096
#define D_ 1024
#define BS_ 16384   // B*S
#define N3_ 3072    // 3*D

__device__ __forceinline__ void gld_lds16(const void* g, void* l) {
    __builtin_amdgcn_global_load_lds(
        (const __attribute__((address_space(1))) void*)g,
        (__attribute__((address_space(3))) void*)l, 16, 0, 0);
}

__device__ __forceinline__ void cast4_one(const float* __restrict__ in,
                                          bf16* __restrict__ out, int i) {
    float4 v = ((const float4*)in)[i];
    union { ushort4 u; bf16 h[4]; } cv;
    cv.h[0] = __float2bfloat16(v.x);
    cv.h[1] = __float2bfloat16(v.y);
    cv.h[2] = __float2bfloat16(v.z);
    cv.h[3] = __float2bfloat16(v.w);
    ((ushort4*)out)[i] = cv.u;
}

// ---- fused prologue: all casts + bias concat + rowsum zero in ONE dispatch ----
__global__ __launch_bounds__(256) void prologue(
    const float* __restrict__ x, const float* __restrict__ wq,
    const float* __restrict__ wk, const float* __restrict__ wv,
    const float* __restrict__ wo, const float* __restrict__ bq,
    const float* __restrict__ bk, const float* __restrict__ bv,
    bf16* __restrict__ xb, bf16* __restrict__ Wc, bf16* __restrict__ Wo,
    float* __restrict__ bc, float* __restrict__ ls) {
    const int blk = blockIdx.x, tid = threadIdx.x;
    if (blk < 16384) {                      // x: 16384*1024/4 float4 chunks
        cast4_one(x, xb, blk * 256 + tid);
    } else if (blk < 20480) {               // 4 weights, 1024 blocks each
        int w = (blk - 16384) >> 10;
        int i = ((blk - 16384) & 1023) * 256 + tid;
        const float* src = (w == 0) ? wq : (w == 1) ? wk : (w == 2) ? wv : wo;
        bf16* dst = (w == 3) ? Wo : Wc + (long)w * D_ * D_;
        cast4_one(src, dst, i);
    } else if (blk < 20544) {               // zero rowsums (16384 floats)
        ls[(blk - 20480) * 256 + tid] = 0.f;
    } else {                                // bias concat (3072)
        for (int i = tid; i < N3_; i += 256)
            bc[i] = (i < 1024) ? bq[i] : (i < 2048) ? bk[i - 1024] : bv[i - 2048];
    }
}

// ---------------- V transpose: per batch, V (4096 x 1024 strided in QKV) -> VT (1024 x 4096)
__global__ __launch_bounds__(256) void transpose_v(const bf16* __restrict__ QKV,
                                                   bf16* __restrict__ VT) {
    __shared__ bf16 t[32][33];
    const int b = blockIdx.z;
    const bf16* Vb = QKV + (long)b * S_ * N3_ + 2048;
    bf16* VTb = VT + (long)b * D_ * S_;
    const int s0 = blockIdx.x * 32, d0 = blockIdx.y * 32;
    const int r = threadIdx.x >> 5, c = threadIdx.x & 31;
#pragma unroll
    for (int i = 0; i < 4; i++)
        t[r + i * 8][c] = Vb[(long)(s0 + r + i * 8) * N3_ + d0 + c];
    __syncthreads();
#pragma unroll
    for (int i = 0; i < 4; i++)
        VTb[(long)(d0 + r + i * 8) * S_ + s0 + c] = t[c][r + i * 8];
}

// ---------------- legacy 128-tile NT GEMM (kept for tier-0/1 fallback paths) ----
template <int EPI, int BM>
__global__ __launch_bounds__(256, 2) void gemm_nt(
    const bf16* __restrict__ A, int lda, long sA,
    const bf16* __restrict__ B, int ldb, long sB,
    void* __restrict__ Cout, int ldc, long sC,
    int K, const float* __restrict__ bias,
    float* __restrict__ rowsum, int sL, float scale) {
    constexpr int MI = BM / 32;
    __shared__ __align__(16) bf16 As[BM * 64];
    __shared__ __align__(16) bf16 Bs[128 * 64];
    const int tid = threadIdx.x;
    const int lane = tid & 63;
    const int wave = tid >> 6;
    const int bz = blockIdx.z;
    const int m0 = blockIdx.x * BM, n0 = blockIdx.y * 128;
    A += (long)bz * sA;
    B += (long)bz * sB;
    rowsum += (long)bz * sL;

    const int wr = (wave >> 1) * (BM / 2);
    const int wc = (wave & 1) * 64;
    const int fm = lane & 15;
    const int q4 = lane >> 4;
    const int sw = fm & 7;
    const int rd0 = ((q4 ^ sw) << 3);
    const int rd1 = (((4 + q4) ^ sw) << 3);

    f32x4 zero = {0.f, 0.f, 0.f, 0.f};
    f32x4 acc[MI][4];
#pragma unroll
    for (int i = 0; i < MI; i++)
#pragma unroll
        for (int j = 0; j < 4; j++) acc[i][j] = zero;

    for (int k0 = 0; k0 < K; k0 += 64) {
#pragma unroll
        for (int t = 0; t < BM / 32; t++) {
            int c = tid + t * 256;
            int row = c >> 3;
            int q = (((c & 7) ^ (row & 7)) << 3);
            gld_lds16(A + (long)(m0 + row) * lda + k0 + q, As + c * 8);
        }
#pragma unroll
        for (int t = 0; t < 4; t++) {
            int c = tid + t * 256;
            int row = c >> 3;
            int q = (((c & 7) ^ (row & 7)) << 3);
            gld_lds16(B + (long)(n0 + row) * ldb + k0 + q, Bs + c * 8);
        }
        __syncthreads();
#pragma unroll
        for (int kh = 0; kh < 2; kh++) {
            const int rdo = kh ? rd1 : rd0;
            bf16x8 af[MI], bfr[4];
#pragma unroll
            for (int i = 0; i < MI; i++)
                af[i] = *(const bf16x8*)(As + (wr + i * 16 + fm) * 64 + rdo);
#pragma unroll
            for (int j = 0; j < 4; j++)
                bfr[j] = *(const bf16x8*)(Bs + (wc + j * 16 + fm) * 64 + rdo);
#pragma unroll
            for (int i = 0; i < MI; i++)
#pragma unroll
                for (int j = 0; j < 4; j++)
                    acc[i][j] = __builtin_amdgcn_mfma_f32_16x16x32_bf16(
                        af[i], bfr[j], acc[i][j], 0, 0, 0);
        }
        __syncthreads();
    }

#pragma unroll
    for (int i = 0; i < MI; i++)
#pragma unroll
        for (int r = 0; r < 4; r++) {
            const int grow = m0 + wr + q4 * 4 + i * 16 + r;
            if constexpr (EPI == 0) {
#pragma unroll
                for (int j = 0; j < 4; j++) {
                    int gcol = n0 + wc + j * 16 + fm;
                    ((bf16*)Cout)[(long)bz * sC + (long)grow * ldc + gcol] =
                        __float2bfloat16(acc[i][j][r] + bias[gcol]);
                }
            } else if constexpr (EPI == 1) {
                float s = 0.f;
#pragma unroll
                for (int j = 0; j < 4; j++) {
                    int gcol = n0 + wc + j * 16 + fm;
                    float v = __expf(acc[i][j][r] * scale);
                    bf16 hv = __float2bfloat16(v);
                    ((bf16*)Cout)[(long)bz * sC + (long)grow * ldc + gcol] = hv;
                    s += __bfloat162float(hv);
                }
                s += __shfl_xor(s, 1, 16);
                s += __shfl_xor(s, 2, 16);
                s += __shfl_xor(s, 4, 16);
                s += __shfl_xor(s, 8, 16);
                if (fm == 0) atomicAdd(rowsum + grow, s);
            } else if constexpr (EPI == 2) {
                float inv = 1.0f / rowsum[grow];
#pragma unroll
                for (int j = 0; j < 4; j++) {
                    int gcol = n0 + wc + j * 16 + fm;
                    ((bf16*)Cout)[(long)bz * sC + (long)grow * ldc + gcol] =
                        __float2bfloat16(acc[i][j][r] * inv);
                }
            } else {
#pragma unroll
                for (int j = 0; j < 4; j++) {
                    int gcol = n0 + wc + j * 16 + fm;
                    ((float*)Cout)[(long)bz * sC + (long)grow * ldc + gcol] =
                        acc[i][j][r] + bias[gcol];
                }
            }
        }
}

// ======================================================================
// 256x256 drain-proof pipelined NT GEMM  (r4)
// r0-r3 forensic: ALL variants cost ~7950 cyc/K-tile regardless of
// swizzle/aliasing/vmcnt placement => model M: the waitcnt pass inserts a
// conservative vmcnt(0) before ds_reads whenever LDS-DMA is outstanding
// (its alias tracking is slot-limited), draining even same-phase loads =>
// ~1400 cyc exposed x4 phases/tile, and at 1 block/CU nothing hides it.
// r4 structure makes that wait free BY CONSTRUCTION:
//   per K-tile: [24 frag ds_reads] -> SB(0) -> [8 gld_lds burst for tile
//   t+1] -> SB(0) -> [64 MFMA] -> SB(0) -> vmcnt(0) -> s_barrier
// - no ds_read ever executes with DMA outstanding (reads precede DMA in
//   final order, pinned by sched_barrier(0); tile entry has vmcnt=0)
// - stage-to-use cover ~2/3 tile (>= HBM latency)
// - ONE barrier per K-tile (was 8); waves free-run inside a tile
// Handoff safety: every ds_read is consumed by MFMA (lgkm wait) before the
// tile-end barrier; each wave vmcnt(0)-drains its own DMA portion before
// arriving; barrier joins => next tile's reads see fully-staged buffer.
// WAR: stages at tile t target the buffer read at t-1, whose reads
// completed before t-1's barrier. LDS swizzle (r1, proven 0 conflicts):
// slot = chunk ^ ((row>>1)&3), src pre-swizzled, dest linear, read offset
// per-thread constant.
// ======================================================================
__device__ __forceinline__ void stage_half(const bf16* __restrict__ g, int ld,
                                           bf16* __restrict__ l, int tid) {
#pragma unroll
    for (int t = 0; t < 2; t++) {
        const int ch = tid + t * 512;                  // 1024 chunks of 16B
        const int row = ch >> 2;
        const int q = (ch ^ (row >> 1)) & 3;           // inverse swizzle on src
        gld_lds16(g + (long)row * ld + (q << 3), l + ch * 8);
    }
}

__device__ __forceinline__ void ds_a4(bf16x8 (&d)[4], const bf16* __restrict__ base,
                                      int ro, int wr, int fm, int rdo) {
#pragma unroll
    for (int i = 0; i < 4; i++)
        d[i] = *(const bf16x8*)(base + (wr + ro + i * 16 + fm) * 32 + rdo);
}

__device__ __forceinline__ void ds_b4(bf16x8 (&d)[4], const bf16* __restrict__ base,
                                      int wc, int fm, int rdo) {
#pragma unroll
    for (int j = 0; j < 4; j++)
        d[j] = *(const bf16x8*)(base + (wc + j * 16 + fm) * 32 + rdo);
}

template <int IO>
__device__ __forceinline__ void mfma16(f32x4 (&acc)[8][4], const bf16x8 (&a)[4],
                                       const bf16x8 (&b)[4]) {
    __builtin_amdgcn_s_setprio(1);
#pragma unroll
    for (int i = 0; i < 4; i++)
#pragma unroll
        for (int j = 0; j < 4; j++)
            acc[IO + i][j] = __builtin_amdgcn_mfma_f32_16x16x32_bf16(
                a[i], b[j], acc[IO + i][j], 0, 0, 0);
    __builtin_amdgcn_s_setprio(0);
}

#define BAR() __builtin_amdgcn_s_barrier()
#define VM0() asm volatile("s_waitcnt vmcnt(0)" ::: "memory")
#define SB0() __builtin_amdgcn_sched_barrier(0)

// one K-tile (K=64): reads cur bufs, burst-prefetches tile kn into nxt bufs
template <bool LAST>
__device__ __forceinline__ void ktile2(
    f32x4 (&acc)[8][4],
    const bf16* __restrict__ Agl, int lda,
    const bf16* __restrict__ Bgl, int ldb, int kn,
    const bf16* __restrict__ cA0, const bf16* __restrict__ cA1,
    const bf16* __restrict__ cB0, const bf16* __restrict__ cB1,
    bf16* __restrict__ nA0, bf16* __restrict__ nA1,
    bf16* __restrict__ nB0, bf16* __restrict__ nB1,
    int tid, int wr, int wc, int fm, int rdo) {
    bf16x8 a0[4], a1[4], b0[4];   // k-half 0 fragments
    bf16x8 c0[4], c1[4], d0[4];   // k-half 1 fragments
    // all 24 fragment ds_reads issue before any DMA (model-M safety)
    ds_a4(a0, cA0, 0, wr, fm, rdo);
    ds_a4(a1, cA0, 64, wr, fm, rdo);
    ds_b4(b0, cB0, wc, fm, rdo);
    ds_a4(c0, cA1, 0, wr, fm, rdo);
    ds_a4(c1, cA1, 64, wr, fm, rdo);
    ds_b4(d0, cB1, wc, fm, rdo);
    SB0();
    if constexpr (!LAST) {
        stage_half(Agl + kn, lda, nA0, tid);
        stage_half(Agl + kn + 32, lda, nA1, tid);
        stage_half(Bgl + kn, ldb, nB0, tid);
        stage_half(Bgl + kn + 32, ldb, nB1, tid);
    }
    SB0();
    mfma16<0>(acc, a0, b0);
    mfma16<4>(acc, a1, b0);
    mfma16<0>(acc, c0, d0);
    mfma16<4>(acc, c1, d0);
    if constexpr (!LAST) {
        SB0();
        VM0();   // drain own DMA portion of tile t+1 before joining barrier
        BAR();
    }
}

template <int EPI>
__global__ __launch_bounds__(512, 2) void gemm8(
    const bf16* __restrict__ A, int lda, long sA,
    const bf16* __restrict__ B, int ldb, long sB,
    void* __restrict__ Cout, int ldc, long sC,
    int K, const float* __restrict__ bias,
    float* __restrict__ rowsum, int sL, float scale) {
    // 8 distinct arrays (16 KiB each, 128 KiB total), static no-alias
    __shared__ __align__(16) bf16 A0h0[256 * 32], A0h1[256 * 32];
    __shared__ __align__(16) bf16 A1h0[256 * 32], A1h1[256 * 32];
    __shared__ __align__(16) bf16 B0h0[256 * 32], B0h1[256 * 32];
    __shared__ __align__(16) bf16 B1h0[256 * 32], B1h1[256 * 32];
    const int tid = threadIdx.x;
    const int lane = tid & 63;
    const int wave = tid >> 6;
    const int bz = blockIdx.z;
    const int m0 = blockIdx.x * 256, n0 = blockIdx.y * 256;
    A += (long)bz * sA + (long)m0 * lda;
    B += (long)bz * sB + (long)n0 * ldb;
    rowsum += (long)bz * sL;

    const int wm = wave >> 2, wn = wave & 3;   // 2M x 4N waves
    const int wr = wm * 128, wc = wn * 64;     // per-wave C block 128x64
    const int fm = lane & 15, q4 = lane >> 4;
    const int rdo = ((q4 ^ ((fm >> 1) & 3)) << 3);

    f32x4 zero = {0.f, 0.f, 0.f, 0.f};
    f32x4 acc[8][4];
#pragma unroll
    for (int i = 0; i < 8; i++)
#pragma unroll
        for (int j = 0; j < 4; j++) acc[i][j] = zero;

    const int NT = K >> 6;   // even (16 or 64) at every call site
    // prologue: stage tile 0, drain, sync
    stage_half(A, lda, A0h0, tid);
    stage_half(A + 32, lda, A0h1, tid);
    stage_half(B, ldb, B0h0, tid);
    stage_half(B + 32, ldb, B0h1, tid);
    VM0();
    BAR();

    int t = 0;
    for (; t + 2 < NT; t += 2) {
        ktile2<false>(acc, A, lda, B, ldb, (t + 1) << 6,
                      A0h0, A0h1, B0h0, B0h1, A1h0, A1h1, B1h0, B1h1,
                      tid, wr, wc, fm, rdo);
        ktile2<false>(acc, A, lda, B, ldb, (t + 2) << 6,
                      A1h0, A1h1, B1h0, B1h1, A0h0, A0h1, B0h0, B0h1,
                      tid, wr, wc, fm, rdo);
    }
    // t == NT-2: full tile staging NT-1, then the peeled last tile
    ktile2<false>(acc, A, lda, B, ldb, (NT - 1) << 6,
                  A0h0, A0h1, B0h0, B0h1, A1h0, A1h1, B1h0, B1h1,
                  tid, wr, wc, fm, rdo);
    ktile2<true>(acc, A, lda, B, ldb, 0,
                 A1h0, A1h1, B1h0, B1h1, A0h0, A0h1, B0h0, B0h1,
                 tid, wr, wc, fm, rdo);

    // C/D layout: col = lane&15, row = (lane>>4)*4 + reg  [m89/m91]
#pragma unroll
    for (int mi = 0; mi < 8; mi++)
#pragma unroll
        for (int r = 0; r < 4; r++) {
            const int grow = m0 + wr + mi * 16 + q4 * 4 + r;
            if constexpr (EPI == 0) {
#pragma unroll
                for (int j = 0; j < 4; j++) {
                    int gcol = n0 + wc + j * 16 + fm;
                    ((bf16*)Cout)[(long)bz * sC + (long)grow * ldc + gcol] =
                        __float2bfloat16(acc[mi][j][r] + bias[gcol]);
                }
            } else if constexpr (EPI == 1) {
                float s = 0.f;
#pragma unroll
                for (int j = 0; j < 4; j++) {
                    int gcol = n0 + wc + j * 16 + fm;
                    float v = __expf(acc[mi][j][r] * scale);
                    bf16 hv = __float2bfloat16(v);
                    ((bf16*)Cout)[(long)bz * sC + (long)grow * ldc + gcol] = hv;
                    s += __bfloat162float(hv);  // sum what we actually stored
                }
                s += __shfl_xor(s, 1, 16);
                s += __shfl_xor(s, 2, 16);
                s += __shfl_xor(s, 4, 16);
                s += __shfl_xor(s, 8, 16);
                if (fm == 0) atomicAdd(rowsum + grow, s);
            } else if constexpr (EPI == 2) {
                float inv = 1.0f / rowsum[grow];
#pragma unroll
                for (int j = 0; j < 4; j++) {
                    int gcol = n0 + wc + j * 16 + fm;
                    ((bf16*)Cout)[(long)bz * sC + (long)grow * ldc + gcol] =
                        __float2bfloat16(acc[mi][j][r] * inv);
                }
            } else {
#pragma unroll
                for (int j = 0; j < 4; j++) {
                    int gcol = n0 + wc + j * 16 + fm;
                    ((float*)Cout)[(long)bz * sC + (long)grow * ldc + gcol] =
                        acc[mi][j][r] + bias[gcol];
                }
            }
        }
}

extern "C" void kernel_launch(void* const* d_in, const int* in_sizes, int n_in,
                              void* d_out, int out_size, void* d_ws, size_t ws_size,
                              hipStream_t stream) {
    const float* x  = (const float*)d_in[0];
    const float* wq = (const float*)d_in[1];
    const float* bq = (const float*)d_in[2];
    const float* wk = (const float*)d_in[3];
    const float* bk = (const float*)d_in[4];
    const float* wv = (const float*)d_in[5];
    const float* bv = (const float*)d_in[6];
    const float* wo = (const float*)d_in[7];
    const float* bo = (const float*)d_in[8];
    (void)in_sizes; (void)n_in; (void)out_size;

    // base ws carve: 104.07 MiB (proven to fit)
    char* p = (char*)d_ws;
    bf16* Wc  = (bf16*)p;  p += (long)N3_ * D_ * 2;   // 6 MiB
    bf16* Wo  = (bf16*)p;  p += (long)D_ * D_ * 2;    // 2 MiB
    float* bc = (float*)p; p += N3_ * 4;              // 12 KiB
    bf16* QKV = (bf16*)p;  p += (long)BS_ * N3_ * 2;  // 96 MiB; Q cols become At
    float* ls = (float*)p; p += (long)BS_ * 4;        // 64 KiB

    bf16* xb = (bf16*)d_out;                          // 32 MiB; dead after QKV GEMM

    const size_t base = 109129728UL;
    int tier;
    bf16 *VT, *E;
    if (ws_size >= base + 134217728UL) {
        tier = 2;
        E  = (bf16*)p;
        VT = (bf16*)((char*)d_out + 33554432);
    } else if (ws_size >= base + 33554432UL) {
        tier = 1;
        VT = (bf16*)p;
        E  = (bf16*)d_out;
    } else {
        tier = 0;
        VT = (bf16*)((char*)d_out + 33554432);
        E  = (bf16*)d_out;
    }

    // 1) fused prologue
    prologue<<<dim3(20545), 256, 0, stream>>>(x, wq, wk, wv, wo, bq, bk, bv,
                                              xb, Wc, Wo, bc, ls);

    // 2) QKV = xb @ Wc^T + bc  (M=16384, N=3072, K=1024)
    gemm8<0><<<dim3(BS_ / 256, N3_ / 256, 1), 512, 0, stream>>>(
        xb, D_, 0, Wc, D_, 0, QKV, N3_, 0, D_, bc, ls, 0, 1.f);

    // 3) VT[b][d][s] = V[b][s][d]
    transpose_v<<<dim3(S_ / 32, D_ / 32, B_), 256, 0, stream>>>(QKV, VT);

    // 4) attention: E = exp(QK^T/32) (+rowsum), At = (E V)/rowsum -> Q region
    if (tier == 2) {
        gemm8<1><<<dim3(16, 16, 4), 512, 0, stream>>>(
            QKV, N3_, (long)S_ * N3_, QKV + 1024, N3_, (long)S_ * N3_,
            E, S_, (long)S_ * S_, D_, nullptr, ls, S_, 0.03125f);
        gemm8<2><<<dim3(16, 4, 4), 512, 0, stream>>>(
            E, S_, (long)S_ * S_, VT, S_, (long)D_ * S_,
            QKV, N3_, (long)S_ * N3_, S_, nullptr, ls, S_, 1.f);
    } else if (tier == 1) {
        for (int pr = 0; pr < 2; ++pr) {
            const long qoff = (long)(2 * pr) * S_ * N3_;
            gemm_nt<1, 128><<<dim3(32, 32, 2), 256, 0, stream>>>(
                QKV + qoff, N3_, (long)S_ * N3_,
                QKV + qoff + 1024, N3_, (long)S_ * N3_,
                E, S_, (long)S_ * S_, D_, nullptr, ls + 2 * pr * S_, S_, 0.03125f);
            gemm_nt<2, 128><<<dim3(32, 8, 2), 256, 0, stream>>>(
                E, S_, (long)S_ * S_,
                VT + (long)(2 * pr) * D_ * S_, S_, (long)D_ * S_,
                QKV + qoff, N3_, (long)S_ * N3_, S_, nullptr, ls + 2 * pr * S_, S_, 1.f);
        }
    } else {
        for (int b = 0; b < B_; ++b) {
            const long qoff = (long)b * S_ * N3_;
            gemm_nt<1, 128><<<dim3(32, 32, 1), 256, 0, stream>>>(
                QKV + qoff, N3_, 0, QKV + qoff + 1024, N3_, 0,
                E, S_, 0, D_, nullptr, ls + b * S_, 0, 0.03125f);
            gemm_nt<2, 64><<<dim3(64, 8, 1), 256, 0, stream>>>(
                E, S_, 0, VT + (long)b * D_ * S_, S_, 0,
                QKV + qoff, N3_, 0, S_, nullptr, ls + b * S_, 0, 1.f);
        }
    }

    // 5) out = At @ Wo^T + bo -> fp32  (M=16384, N=1024, K=1024)
    gemm8<3><<<dim3(BS_ / 256, D_ / 256, 1), 512, 0, stream>>>(
        QKV, N3_, 0, Wo, D_, 0, d_out, D_, 0, D_, bo, ls, 0, 1.f);
}

// Round 5
// 597.758 us; speedup vs baseline: 1.0921x; 1.0921x over previous
//
#include <hip/hip_runtime.h>
#include <hip/hip_bf16.h>

typedef __hip_bfloat16 bf16;
typedef __bf16 bf16x8 __attribute__((ext_vector_type(8)));
typedef float f32x4 __attribute__((ext_vector_type(4)));

#define B_ 4
#define S_ 4096
#define D_ 1024
#define BS_ 16384   // B*S
#define N3_ 3072    // 3*D

__device__ __forceinline__ void gld_lds16(const void* g, void* l) {
    __builtin_amdgcn_global_load_lds(
        (const __attribute__((address_space(1))) void*)g,
        (__attribute__((address_space(3))) void*)l, 16, 0, 0);
}

__device__ __forceinline__ void cast4_one(const float* __restrict__ in,
                                          bf16* __restrict__ out, int i) {
    float4 v = ((const float4*)in)[i];
    union { ushort4 u; bf16 h[4]; } cv;
    cv.h[0] = __float2bfloat16(v.x);
    cv.h[1] = __float2bfloat16(v.y);
    cv.h[2] = __float2bfloat16(v.z);
    cv.h[3] = __float2bfloat16(v.w);
    ((ushort4*)out)[i] = cv.u;
}

// ---- fused prologue: all casts + bias concat + rowsum zero in ONE dispatch ----
__global__ __launch_bounds__(256) void prologue(
    const float* __restrict__ x, const float* __restrict__ wq,
    const float* __restrict__ wk, const float* __restrict__ wv,
    const float* __restrict__ wo, const float* __restrict__ bq,
    const float* __restrict__ bk, const float* __restrict__ bv,
    bf16* __restrict__ xb, bf16* __restrict__ Wc, bf16* __restrict__ Wo,
    float* __restrict__ bc, float* __restrict__ ls) {
    const int blk = blockIdx.x, tid = threadIdx.x;
    if (blk < 16384) {                      // x: 16384*1024/4 float4 chunks
        cast4_one(x, xb, blk * 256 + tid);
    } else if (blk < 20480) {               // 4 weights, 1024 blocks each
        int w = (blk - 16384) >> 10;
        int i = ((blk - 16384) & 1023) * 256 + tid;
        const float* src = (w == 0) ? wq : (w == 1) ? wk : (w == 2) ? wv : wo;
        bf16* dst = (w == 3) ? Wo : Wc + (long)w * D_ * D_;
        cast4_one(src, dst, i);
    } else if (blk < 20544) {               // zero rowsums (16384 floats)
        ls[(blk - 20480) * 256 + tid] = 0.f;
    } else {                                // bias concat (3072)
        for (int i = tid; i < N3_; i += 256)
            bc[i] = (i < 1024) ? bq[i] : (i < 2048) ? bk[i - 1024] : bv[i - 2048];
    }
}

// ---------------- standalone V transpose (tier-0/1 fallback only) ----------------
__global__ __launch_bounds__(256) void transpose_v(const bf16* __restrict__ QKV,
                                                   bf16* __restrict__ VT) {
    __shared__ bf16 t[32][33];
    const int b = blockIdx.z;
    const bf16* Vb = QKV + (long)b * S_ * N3_ + 2048;
    bf16* VTb = VT + (long)b * D_ * S_;
    const int s0 = blockIdx.x * 32, d0 = blockIdx.y * 32;
    const int r = threadIdx.x >> 5, c = threadIdx.x & 31;
#pragma unroll
    for (int i = 0; i < 4; i++)
        t[r + i * 8][c] = Vb[(long)(s0 + r + i * 8) * N3_ + d0 + c];
    __syncthreads();
#pragma unroll
    for (int i = 0; i < 4; i++)
        VTb[(long)(d0 + r + i * 8) * S_ + s0 + c] = t[c][r + i * 8];
}

// ---------------- NT GEMM: C(M x 128-col tiles) = A(MxK) * B(NxK)^T, BM x 128 tile, BK=64 ----
// Proven r0 structure (m97-ceiling ~916 TF; within-structure levers are measured-null).
// LDS rows are 128B (full bank wrap): XOR chunk-col with (row&7); 2 lanes/bank = free [m136].
// EPI 0: +bias, bf16 | 1: exp*scale, bf16 + atomic rowsum | 2: /rowsum, bf16 | 3: +bias, fp32
// EPI 1 extra (tier-2): grid y==32 slice blocks perform the V-transpose (VT[b][d][s]=V[b][s][d])
// concurrently with the scores GEMM, overlaid on the As/Bs LDS via union — removes the
// serial transpose_v dispatch (~15us of idle MFMA).
template <int EPI, int BM>
__global__ __launch_bounds__(256, 2) void gemm_nt(
    const bf16* __restrict__ A, int lda, long sA,
    const bf16* __restrict__ B, int ldb, long sB,
    void* __restrict__ Cout, int ldc, long sC,
    int K, const float* __restrict__ bias,
    float* __restrict__ rowsum, int sL, float scale,
    bf16* __restrict__ vt) {
    union __align__(16) SMem {
        struct { bf16 As[BM * 64]; bf16 Bs[128 * 64]; } g;  // 16/8 + 16 KiB
        bf16 T[8][32][40];                                  // 20.5 KiB transpose tiles
    };
    __shared__ SMem sm;

    if constexpr (EPI == 1) {
        if (blockIdx.y == 32) {   // fused V-transpose slice (tier-2 only: 32x4 blocks)
            const int bz2 = blockIdx.z;
            const bf16* Vb = A + (long)bz2 * sA + 2048;      // A == QKV base
            bf16* VTb = vt + (long)bz2 * D_ * S_;
            const int tile = threadIdx.x >> 5, t32 = threadIdx.x & 31;
            for (int it = 0; it < 16; ++it) {
                const int ti = it * 8 + tile;                 // 128 32x32 tiles/block
                const int s0 = blockIdx.x * 128 + (ti & 3) * 32;
                const int d0 = (ti >> 2) * 32;
#pragma unroll
                for (int c = 0; c < 4; ++c)                   // vector load, row-major LDS
                    *(bf16x8*)&sm.T[tile][t32][c * 8] =
                        *(const bf16x8*)(Vb + (long)(s0 + t32) * N3_ + d0 + c * 8);
                __syncthreads();
                union { bf16x8 v[4]; bf16 h[32]; } col;
#pragma unroll
                for (int s = 0; s < 32; ++s) col.h[s] = sm.T[tile][s][t32];
#pragma unroll
                for (int c = 0; c < 4; ++c)                   // vector store of column
                    *(bf16x8*)(VTb + (long)(d0 + t32) * S_ + s0 + c * 8) = col.v[c];
                __syncthreads();
            }
            return;
        }
    }
    (void)vt;

    constexpr int MI = BM / 32;                 // 16-row fragment blocks per wave (rows)
    bf16* __restrict__ As = sm.g.As;
    bf16* __restrict__ Bs = sm.g.Bs;
    const int tid = threadIdx.x;
    const int lane = tid & 63;
    const int wave = tid >> 6;
    const int bz = blockIdx.z;
    const int m0 = blockIdx.x * BM, n0 = blockIdx.y * 128;
    A += (long)bz * sA;
    B += (long)bz * sB;
    rowsum += (long)bz * sL;

    const int wr = (wave >> 1) * (BM / 2);
    const int wc = (wave & 1) * 64;
    const int fm = lane & 15;
    const int q4 = lane >> 4;
    const int sw = fm & 7;                       // row&7 for all fragment rows
    const int rd0 = ((q4 ^ sw) << 3);            // k-half 0 chunk offset (elements)
    const int rd1 = (((4 + q4) ^ sw) << 3);      // k-half 1 chunk offset

    f32x4 zero = {0.f, 0.f, 0.f, 0.f};
    f32x4 acc[MI][4];
#pragma unroll
    for (int i = 0; i < MI; i++)
#pragma unroll
        for (int j = 0; j < 4; j++) acc[i][j] = zero;

    for (int k0 = 0; k0 < K; k0 += 64) {
        // stage A: BM*8 16B-chunks; LDS slot c is fixed, global chunk-col is XOR-swizzled
#pragma unroll
        for (int t = 0; t < BM / 32; t++) {
            int c = tid + t * 256;
            int row = c >> 3;
            int q = (((c & 7) ^ (row & 7)) << 3);
            gld_lds16(A + (long)(m0 + row) * lda + k0 + q, As + c * 8);
        }
#pragma unroll
        for (int t = 0; t < 4; t++) {
            int c = tid + t * 256;
            int row = c >> 3;
            int q = (((c & 7) ^ (row & 7)) << 3);
            gld_lds16(B + (long)(n0 + row) * ldb + k0 + q, Bs + c * 8);
        }
        __syncthreads();
#pragma unroll
        for (int kh = 0; kh < 2; kh++) {
            const int rdo = kh ? rd1 : rd0;
            bf16x8 af[MI], bfr[4];
#pragma unroll
            for (int i = 0; i < MI; i++)
                af[i] = *(const bf16x8*)(As + (wr + i * 16 + fm) * 64 + rdo);
#pragma unroll
            for (int j = 0; j < 4; j++)
                bfr[j] = *(const bf16x8*)(Bs + (wc + j * 16 + fm) * 64 + rdo);
#pragma unroll
            for (int i = 0; i < MI; i++)
#pragma unroll
                for (int j = 0; j < 4; j++)
                    acc[i][j] = __builtin_amdgcn_mfma_f32_16x16x32_bf16(
                        af[i], bfr[j], acc[i][j], 0, 0, 0);
        }
        __syncthreads();
    }

    // C/D layout: col = lane&15, row = (lane>>4)*4 + reg  [m89/m91]
#pragma unroll
    for (int i = 0; i < MI; i++)
#pragma unroll
        for (int r = 0; r < 4; r++) {
            const int grow = m0 + wr + q4 * 4 + i * 16 + r;
            if constexpr (EPI == 0) {
#pragma unroll
                for (int j = 0; j < 4; j++) {
                    int gcol = n0 + wc + j * 16 + fm;
                    ((bf16*)Cout)[(long)bz * sC + (long)grow * ldc + gcol] =
                        __float2bfloat16(acc[i][j][r] + bias[gcol]);
                }
            } else if constexpr (EPI == 1) {
                float s = 0.f;
#pragma unroll
                for (int j = 0; j < 4; j++) {
                    int gcol = n0 + wc + j * 16 + fm;
                    float v = __expf(acc[i][j][r] * scale);
                    bf16 hv = __float2bfloat16(v);
                    ((bf16*)Cout)[(long)bz * sC + (long)grow * ldc + gcol] = hv;
                    s += __bfloat162float(hv);  // sum what we actually stored
                }
                s += __shfl_xor(s, 1, 16);
                s += __shfl_xor(s, 2, 16);
                s += __shfl_xor(s, 4, 16);
                s += __shfl_xor(s, 8, 16);
                if (fm == 0) atomicAdd(rowsum + grow, s);
            } else if constexpr (EPI == 2) {
                float inv = 1.0f / rowsum[grow];
#pragma unroll
                for (int j = 0; j < 4; j++) {
                    int gcol = n0 + wc + j * 16 + fm;
                    ((bf16*)Cout)[(long)bz * sC + (long)grow * ldc + gcol] =
                        __float2bfloat16(acc[i][j][r] * inv);
                }
            } else {
#pragma unroll
                for (int j = 0; j < 4; j++) {
                    int gcol = n0 + wc + j * 16 + fm;
                    ((float*)Cout)[(long)bz * sC + (long)grow * ldc + gcol] =
                        acc[i][j][r] + bias[gcol];
                }
            }
        }
}

extern "C" void kernel_launch(void* const* d_in, const int* in_sizes, int n_in,
                              void* d_out, int out_size, void* d_ws, size_t ws_size,
                              hipStream_t stream) {
    const float* x  = (const float*)d_in[0];
    const float* wq = (const float*)d_in[1];
    const float* bq = (const float*)d_in[2];
    const float* wk = (const float*)d_in[3];
    const float* bk = (const float*)d_in[4];
    const float* wv = (const float*)d_in[5];
    const float* bv = (const float*)d_in[6];
    const float* wo = (const float*)d_in[7];
    const float* bo = (const float*)d_in[8];
    (void)in_sizes; (void)n_in; (void)out_size;

    // base ws carve: 104.07 MiB (proven to fit)
    char* p = (char*)d_ws;
    bf16* Wc  = (bf16*)p;  p += (long)N3_ * D_ * 2;   // 6 MiB
    bf16* Wo  = (bf16*)p;  p += (long)D_ * D_ * 2;    // 2 MiB
    float* bc = (float*)p; p += N3_ * 4;              // 12 KiB
    bf16* QKV = (bf16*)p;  p += (long)BS_ * N3_ * 2;  // 96 MiB; Q cols become At
    float* ls = (float*)p; p += (long)BS_ * 4;        // 64 KiB
    // base end = 109,129,728 bytes

    bf16* xb = (bf16*)d_out;                          // 32 MiB; dead after QKV GEMM

    const size_t base = 109129728UL;
    int tier;
    bf16 *VT, *E;
    if (ws_size >= base + 134217728UL) {
        tier = 2;
        E  = (bf16*)p;                                // 128 MiB in ws
        VT = (bf16*)((char*)d_out + 33554432);        // 32 MiB upper half of d_out
    } else if (ws_size >= base + 33554432UL) {
        tier = 1;
        VT = (bf16*)p;                                // 32 MiB in ws
        E  = (bf16*)d_out;                            // 2 slots x 32 MiB
    } else {
        tier = 0;
        VT = (bf16*)((char*)d_out + 33554432);
        E  = (bf16*)d_out;                            // 1 slot
    }

    // 1) fused prologue
    prologue<<<dim3(20545), 256, 0, stream>>>(x, wq, wk, wv, wo, bq, bk, bv,
                                              xb, Wc, Wo, bc, ls);

    // 2) QKV = xb @ Wc^T + bc  (M=16384, N=3072, K=1024)
    gemm_nt<0, 128><<<dim3(BS_ / 128, N3_ / 128, 1), 256, 0, stream>>>(
        xb, D_, 0, Wc, D_, 0, QKV, N3_, 0, D_, bc, ls, 0, 1.f, nullptr);

    // 3+4) attention: E = exp(QK^T/32) (+rowsum, + fused V-transpose slice at tier 2),
    //      At = (E V)/rowsum -> Q region
    if (tier == 2) {
        gemm_nt<1, 128><<<dim3(32, 33, 4), 256, 0, stream>>>(
            QKV, N3_, (long)S_ * N3_, QKV + 1024, N3_, (long)S_ * N3_,
            E, S_, (long)S_ * S_, D_, nullptr, ls, S_, 0.03125f, VT);
        gemm_nt<2, 128><<<dim3(32, 8, 4), 256, 0, stream>>>(
            E, S_, (long)S_ * S_, VT, S_, (long)D_ * S_,
            QKV, N3_, (long)S_ * N3_, S_, nullptr, ls, S_, 1.f, nullptr);
    } else if (tier == 1) {
        transpose_v<<<dim3(S_ / 32, D_ / 32, B_), 256, 0, stream>>>(QKV, VT);
        for (int pr = 0; pr < 2; ++pr) {
            const long qoff = (long)(2 * pr) * S_ * N3_;
            gemm_nt<1, 128><<<dim3(32, 32, 2), 256, 0, stream>>>(
                QKV + qoff, N3_, (long)S_ * N3_,
                QKV + qoff + 1024, N3_, (long)S_ * N3_,
                E, S_, (long)S_ * S_, D_, nullptr, ls + 2 * pr * S_, S_, 0.03125f, nullptr);
            gemm_nt<2, 128><<<dim3(32, 8, 2), 256, 0, stream>>>(
                E, S_, (long)S_ * S_,
                VT + (long)(2 * pr) * D_ * S_, S_, (long)D_ * S_,
                QKV + qoff, N3_, (long)S_ * N3_, S_, nullptr, ls + 2 * pr * S_, S_, 1.f, nullptr);
        }
    } else {
        transpose_v<<<dim3(S_ / 32, D_ / 32, B_), 256, 0, stream>>>(QKV, VT);
        for (int b = 0; b < B_; ++b) {
            const long qoff = (long)b * S_ * N3_;
            gemm_nt<1, 128><<<dim3(32, 32, 1), 256, 0, stream>>>(
                QKV + qoff, N3_, 0, QKV + qoff + 1024, N3_, 0,
                E, S_, 0, D_, nullptr, ls + b * S_, 0, 0.03125f, nullptr);
            gemm_nt<2, 64><<<dim3(64, 8, 1), 256, 0, stream>>>(
                E, S_, 0, VT + (long)b * D_ * S_, S_, 0,
                QKV + qoff, N3_, 0, S_, nullptr, ls + b * S_, 0, 1.f, nullptr);
        }
    }

    // 5) out = At @ Wo^T + bo -> fp32  (M=16384, N=1024, K=1024; A row stride 3072)
    gemm_nt<3, 128><<<dim3(BS_ / 128, D_ / 128, 1), 256, 0, stream>>>(
        QKV, N3_, 0, Wo, D_, 0, d_out, D_, 0, D_, bo, ls, 0, 1.f, nullptr);
}

// Round 6
// 581.833 us; speedup vs baseline: 1.1220x; 1.0274x over previous
//
#include <hip/hip_runtime.h>
#include <hip/hip_bf16.h>

typedef __hip_bfloat16 bf16;
typedef __bf16 bf16x8 __attribute__((ext_vector_type(8)));
typedef float f32x4 __attribute__((ext_vector_type(4)));

#define B_ 4
#define S_ 4096
#define D_ 1024
#define BS_ 16384   // B*S
#define N3_ 3072    // 3*D

__device__ __forceinline__ void gld_lds16(const void* g, void* l) {
    __builtin_amdgcn_global_load_lds(
        (const __attribute__((address_space(1))) void*)g,
        (__attribute__((address_space(3))) void*)l, 16, 0, 0);
}

__device__ __forceinline__ void cast4_one(const float* __restrict__ in,
                                          bf16* __restrict__ out, int i) {
    float4 v = ((const float4*)in)[i];
    union { ushort4 u; bf16 h[4]; } cv;
    cv.h[0] = __float2bfloat16(v.x);
    cv.h[1] = __float2bfloat16(v.y);
    cv.h[2] = __float2bfloat16(v.z);
    cv.h[3] = __float2bfloat16(v.w);
    ((ushort4*)out)[i] = cv.u;
}

// ---- fused prologue: all casts + bias concat + rowsum zero in ONE dispatch ----
__global__ __launch_bounds__(256) void prologue(
    const float* __restrict__ x, const float* __restrict__ wq,
    const float* __restrict__ wk, const float* __restrict__ wv,
    const float* __restrict__ wo, const float* __restrict__ bq,
    const float* __restrict__ bk, const float* __restrict__ bv,
    bf16* __restrict__ xb, bf16* __restrict__ Wc, bf16* __restrict__ Wo,
    float* __restrict__ bc, float* __restrict__ ls) {
    const int blk = blockIdx.x, tid = threadIdx.x;
    if (blk < 16384) {                      // x: 16384*1024/4 float4 chunks
        cast4_one(x, xb, blk * 256 + tid);
    } else if (blk < 20480) {               // 4 weights, 1024 blocks each
        int w = (blk - 16384) >> 10;
        int i = ((blk - 16384) & 1023) * 256 + tid;
        const float* src = (w == 0) ? wq : (w == 1) ? wk : (w == 2) ? wv : wo;
        bf16* dst = (w == 3) ? Wo : Wc + (long)w * D_ * D_;
        cast4_one(src, dst, i);
    } else if (blk < 20544) {               // zero rowsums (16384 floats)
        ls[(blk - 20480) * 256 + tid] = 0.f;
    } else {                                // bias concat (3072)
        for (int i = tid; i < N3_; i += 256)
            bc[i] = (i < 1024) ? bq[i] : (i < 2048) ? bk[i - 1024] : bv[i - 2048];
    }
}

// ---------------- NT GEMM: C(M x 128-col tiles) = A(MxK) * B(NxK)^T, BM x 128 tile, BK=64 ----
// Proven r0 structure (m97-ceiling ~916 TF; within-structure levers measured-null r1-r4).
// LDS rows are 128B (full bank wrap): XOR chunk-col with (row&7); 2 lanes/bank = free [m136].
// EPI 0: +bias, bf16 | 1: exp*scale, bf16 + atomic rowsum | 2: /rowsum, bf16 | 3: +bias, fp32
// EPI 4 (r6): V projection with DIRECT-TRANSPOSED output. C columns are V's d-dim; MFMA
// C-layout makes r=0..3 consecutive rows (s-dim) -> pack ushort4 and store to
// VT[bz][d][s] (8B/lane; lanes q4=0..3 form 32B contiguous segments, i*16 extends runs).
// Replaces the transpose_v dispatch AND V's 32+32 MiB QKV round trip.
template <int EPI, int BM>
__global__ __launch_bounds__(256, 2) void gemm_nt(
    const bf16* __restrict__ A, int lda, long sA,
    const bf16* __restrict__ B, int ldb, long sB,
    void* __restrict__ Cout, int ldc, long sC,
    int K, const float* __restrict__ bias,
    float* __restrict__ rowsum, int sL, float scale) {
    constexpr int MI = BM / 32;                 // 16-row fragment blocks per wave (rows)
    __shared__ __align__(16) bf16 As[BM * 64];  // BM=128: 16 KB, BM=64: 8 KB
    __shared__ __align__(16) bf16 Bs[128 * 64]; // 16 KB
    const int tid = threadIdx.x;
    const int lane = tid & 63;
    const int wave = tid >> 6;
    const int bz = blockIdx.z;
    const int m0 = blockIdx.x * BM, n0 = blockIdx.y * 128;
    A += (long)bz * sA;
    B += (long)bz * sB;
    rowsum += (long)bz * sL;

    const int wr = (wave >> 1) * (BM / 2);
    const int wc = (wave & 1) * 64;
    const int fm = lane & 15;
    const int q4 = lane >> 4;
    const int sw = fm & 7;                       // row&7 for all fragment rows
    const int rd0 = ((q4 ^ sw) << 3);            // k-half 0 chunk offset (elements)
    const int rd1 = (((4 + q4) ^ sw) << 3);      // k-half 1 chunk offset

    f32x4 zero = {0.f, 0.f, 0.f, 0.f};
    f32x4 acc[MI][4];
#pragma unroll
    for (int i = 0; i < MI; i++)
#pragma unroll
        for (int j = 0; j < 4; j++) acc[i][j] = zero;

    for (int k0 = 0; k0 < K; k0 += 64) {
        // stage A: BM*8 16B-chunks; LDS slot c is fixed, global chunk-col is XOR-swizzled
#pragma unroll
        for (int t = 0; t < BM / 32; t++) {
            int c = tid + t * 256;
            int row = c >> 3;
            int q = (((c & 7) ^ (row & 7)) << 3);
            gld_lds16(A + (long)(m0 + row) * lda + k0 + q, As + c * 8);
        }
#pragma unroll
        for (int t = 0; t < 4; t++) {
            int c = tid + t * 256;
            int row = c >> 3;
            int q = (((c & 7) ^ (row & 7)) << 3);
            gld_lds16(B + (long)(n0 + row) * ldb + k0 + q, Bs + c * 8);
        }
        __syncthreads();
#pragma unroll
        for (int kh = 0; kh < 2; kh++) {
            const int rdo = kh ? rd1 : rd0;
            bf16x8 af[MI], bfr[4];
#pragma unroll
            for (int i = 0; i < MI; i++)
                af[i] = *(const bf16x8*)(As + (wr + i * 16 + fm) * 64 + rdo);
#pragma unroll
            for (int j = 0; j < 4; j++)
                bfr[j] = *(const bf16x8*)(Bs + (wc + j * 16 + fm) * 64 + rdo);
#pragma unroll
            for (int i = 0; i < MI; i++)
#pragma unroll
                for (int j = 0; j < 4; j++)
                    acc[i][j] = __builtin_amdgcn_mfma_f32_16x16x32_bf16(
                        af[i], bfr[j], acc[i][j], 0, 0, 0);
        }
        __syncthreads();
    }

    // C/D layout: col = lane&15, row = (lane>>4)*4 + reg  [m89/m91]
    if constexpr (EPI == 4) {
        // transposed V write: Cout = VT (bz batch), ldc = S_; sC = D_*S_
#pragma unroll
        for (int i = 0; i < MI; i++) {
            const int s0w = m0 + wr + i * 16 + q4 * 4;
#pragma unroll
            for (int j = 0; j < 4; j++) {
                const int gcol = n0 + wc + j * 16 + fm;   // V's d index
                const float bv = bias[gcol];
                union { ushort4 u; bf16 h[4]; } pk;
#pragma unroll
                for (int r = 0; r < 4; r++)
                    pk.h[r] = __float2bfloat16(acc[i][j][r] + bv);
                *(ushort4*)((bf16*)Cout + (long)bz * sC + (long)gcol * ldc + s0w) = pk.u;
            }
        }
        return;
    }

#pragma unroll
    for (int i = 0; i < MI; i++)
#pragma unroll
        for (int r = 0; r < 4; r++) {
            const int grow = m0 + wr + q4 * 4 + i * 16 + r;
            if constexpr (EPI == 0) {
#pragma unroll
                for (int j = 0; j < 4; j++) {
                    int gcol = n0 + wc + j * 16 + fm;
                    ((bf16*)Cout)[(long)bz * sC + (long)grow * ldc + gcol] =
                        __float2bfloat16(acc[i][j][r] + bias[gcol]);
                }
            } else if constexpr (EPI == 1) {
                float s = 0.f;
#pragma unroll
                for (int j = 0; j < 4; j++) {
                    int gcol = n0 + wc + j * 16 + fm;
                    float v = __expf(acc[i][j][r] * scale);
                    bf16 hv = __float2bfloat16(v);
                    ((bf16*)Cout)[(long)bz * sC + (long)grow * ldc + gcol] = hv;
                    s += __bfloat162float(hv);  // sum what we actually stored
                }
                s += __shfl_xor(s, 1, 16);
                s += __shfl_xor(s, 2, 16);
                s += __shfl_xor(s, 4, 16);
                s += __shfl_xor(s, 8, 16);
                if (fm == 0) atomicAdd(rowsum + grow, s);
            } else if constexpr (EPI == 2) {
                float inv = 1.0f / rowsum[grow];
#pragma unroll
                for (int j = 0; j < 4; j++) {
                    int gcol = n0 + wc + j * 16 + fm;
                    ((bf16*)Cout)[(long)bz * sC + (long)grow * ldc + gcol] =
                        __float2bfloat16(acc[i][j][r] * inv);
                }
            } else {
#pragma unroll
                for (int j = 0; j < 4; j++) {
                    int gcol = n0 + wc + j * 16 + fm;
                    ((float*)Cout)[(long)bz * sC + (long)grow * ldc + gcol] =
                        acc[i][j][r] + bias[gcol];
                }
            }
        }
}

extern "C" void kernel_launch(void* const* d_in, const int* in_sizes, int n_in,
                              void* d_out, int out_size, void* d_ws, size_t ws_size,
                              hipStream_t stream) {
    const float* x  = (const float*)d_in[0];
    const float* wq = (const float*)d_in[1];
    const float* bq = (const float*)d_in[2];
    const float* wk = (const float*)d_in[3];
    const float* bk = (const float*)d_in[4];
    const float* wv = (const float*)d_in[5];
    const float* bv = (const float*)d_in[6];
    const float* wo = (const float*)d_in[7];
    const float* bo = (const float*)d_in[8];
    (void)in_sizes; (void)n_in; (void)out_size;

    // base ws carve: 104.07 MiB (proven to fit)
    char* p = (char*)d_ws;
    bf16* Wc  = (bf16*)p;  p += (long)N3_ * D_ * 2;   // 6 MiB
    bf16* Wo  = (bf16*)p;  p += (long)D_ * D_ * 2;    // 2 MiB
    float* bc = (float*)p; p += N3_ * 4;              // 12 KiB
    bf16* QKV = (bf16*)p;  p += (long)BS_ * N3_ * 2;  // 96 MiB; Q cols become At
    float* ls = (float*)p; p += (long)BS_ * 4;        // 64 KiB
    // base end = 109,129,728 bytes

    bf16* xb = (bf16*)d_out;                          // 32 MiB; dead after QKV GEMM

    const size_t base = 109129728UL;
    int tier;
    bf16 *VT, *E;
    if (ws_size >= base + 134217728UL) {
        tier = 2;
        E  = (bf16*)p;                                // 128 MiB in ws
        VT = (bf16*)((char*)d_out + 33554432);        // 32 MiB upper half of d_out
    } else if (ws_size >= base + 33554432UL) {
        tier = 1;
        VT = (bf16*)p;                                // 32 MiB in ws
        E  = (bf16*)d_out;                            // 2 slots x 32 MiB
    } else {
        tier = 0;
        VT = (bf16*)((char*)d_out + 33554432);
        E  = (bf16*)d_out;                            // 1 slot
    }
    // VT is disjoint from xb (lower 32 MiB of d_out) in every tier, so the
    // V-projection GEMM may write VT while reading xb.

    // 1) fused prologue
    prologue<<<dim3(20545), 256, 0, stream>>>(x, wq, wk, wv, wo, bq, bk, bv,
                                              xb, Wc, Wo, bc, ls);

    // 2a) Q,K = xb @ Wqk^T + b  (M=16384, N=2048, K=1024) -> QKV cols [0,2048)
    gemm_nt<0, 128><<<dim3(BS_ / 128, 16, 1), 256, 0, stream>>>(
        xb, D_, 0, Wc, D_, 0, QKV, N3_, 0, D_, bc, ls, 0, 1.f);
    // 2b) V = xb @ Wv^T + bv, written TRANSPOSED per batch: VT[b][d][s]
    //     (z = batch; A strided S_*D_ into xb; B = Wv rows of Wc)
    gemm_nt<4, 128><<<dim3(S_ / 128, 8, B_), 256, 0, stream>>>(
        xb, D_, (long)S_ * D_, Wc + (long)2048 * D_, D_, 0,
        VT, S_, (long)D_ * S_, D_, bc + 2048, ls, 0, 1.f);

    // 3) attention: E = exp(QK^T/32) (+rowsum), At = (E V)/rowsum -> Q region
    if (tier == 2) {
        gemm_nt<1, 128><<<dim3(32, 32, 4), 256, 0, stream>>>(
            QKV, N3_, (long)S_ * N3_, QKV + 1024, N3_, (long)S_ * N3_,
            E, S_, (long)S_ * S_, D_, nullptr, ls, S_, 0.03125f);
        gemm_nt<2, 128><<<dim3(32, 8, 4), 256, 0, stream>>>(
            E, S_, (long)S_ * S_, VT, S_, (long)D_ * S_,
            QKV, N3_, (long)S_ * N3_, S_, nullptr, ls, S_, 1.f);
    } else if (tier == 1) {
        for (int pr = 0; pr < 2; ++pr) {
            const long qoff = (long)(2 * pr) * S_ * N3_;
            gemm_nt<1, 128><<<dim3(32, 32, 2), 256, 0, stream>>>(
                QKV + qoff, N3_, (long)S_ * N3_,
                QKV + qoff + 1024, N3_, (long)S_ * N3_,
                E, S_, (long)S_ * S_, D_, nullptr, ls + 2 * pr * S_, S_, 0.03125f);
            gemm_nt<2, 128><<<dim3(32, 8, 2), 256, 0, stream>>>(
                E, S_, (long)S_ * S_,
                VT + (long)(2 * pr) * D_ * S_, S_, (long)D_ * S_,
                QKV + qoff, N3_, (long)S_ * N3_, S_, nullptr, ls + 2 * pr * S_, S_, 1.f);
        }
    } else {
        for (int b = 0; b < B_; ++b) {
            const long qoff = (long)b * S_ * N3_;
            gemm_nt<1, 128><<<dim3(32, 32, 1), 256, 0, stream>>>(
                QKV + qoff, N3_, 0, QKV + qoff + 1024, N3_, 0,
                E, S_, 0, D_, nullptr, ls + b * S_, 0, 0.03125f);
            gemm_nt<2, 64><<<dim3(64, 8, 1), 256, 0, stream>>>(
                E, S_, 0, VT + (long)b * D_ * S_, S_, 0,
                QKV + qoff, N3_, 0, S_, nullptr, ls + b * S_, 0, 1.f);
        }
    }

    // 5) out = At @ Wo^T + bo -> fp32  (M=16384, N=1024, K=1024; A row stride 3072)
    gemm_nt<3, 128><<<dim3(BS_ / 128, D_ / 128, 1), 256, 0, stream>>>(
        QKV, N3_, 0, Wo, D_, 0, d_out, D_, 0, D_, bo, ls, 0, 1.f);
}

// Round 7
// 547.909 us; speedup vs baseline: 1.1915x; 1.0619x over previous
//
#include <hip/hip_runtime.h>
#include <hip/hip_bf16.h>

typedef __hip_bfloat16 bf16;
typedef __bf16 bf16x8 __attribute__((ext_vector_type(8)));
typedef float f32x4 __attribute__((ext_vector_type(4)));

#define B_ 4
#define S_ 4096
#define D_ 1024
#define BS_ 16384   // B*S
#define N3_ 3072    // 3*D

__device__ __forceinline__ void gld_lds16(const void* g, void* l) {
    __builtin_amdgcn_global_load_lds(
        (const __attribute__((address_space(1))) void*)g,
        (__attribute__((address_space(3))) void*)l, 16, 0, 0);
}

__device__ __forceinline__ void cast4_one(const float* __restrict__ in,
                                          bf16* __restrict__ out, int i) {
    float4 v = ((const float4*)in)[i];
    union { ushort4 u; bf16 h[4]; } cv;
    cv.h[0] = __float2bfloat16(v.x);
    cv.h[1] = __float2bfloat16(v.y);
    cv.h[2] = __float2bfloat16(v.z);
    cv.h[3] = __float2bfloat16(v.w);
    ((ushort4*)out)[i] = cv.u;
}

// ---- fused prologue: all casts + bias concat + rowsum zero in ONE dispatch ----
__global__ __launch_bounds__(256) void prologue(
    const float* __restrict__ x, const float* __restrict__ wq,
    const float* __restrict__ wk, const float* __restrict__ wv,
    const float* __restrict__ wo, const float* __restrict__ bq,
    const float* __restrict__ bk, const float* __restrict__ bv,
    bf16* __restrict__ xb, bf16* __restrict__ Wc, bf16* __restrict__ Wo,
    float* __restrict__ bc, float* __restrict__ ls) {
    const int blk = blockIdx.x, tid = threadIdx.x;
    if (blk < 16384) {                      // x: 16384*1024/4 float4 chunks
        cast4_one(x, xb, blk * 256 + tid);
    } else if (blk < 20480) {               // 4 weights, 1024 blocks each
        int w = (blk - 16384) >> 10;
        int i = ((blk - 16384) & 1023) * 256 + tid;
        const float* src = (w == 0) ? wq : (w == 1) ? wk : (w == 2) ? wv : wo;
        bf16* dst = (w == 3) ? Wo : Wc + (long)w * D_ * D_;
        cast4_one(src, dst, i);
    } else if (blk < 20544) {               // zero rowsums (16384 floats)
        ls[(blk - 20480) * 256 + tid] = 0.f;
    } else {                                // bias concat (3072)
        for (int i = tid; i < N3_; i += 256)
            bc[i] = (i < 1024) ? bq[i] : (i < 2048) ? bk[i - 1024] : bv[i - 2048];
    }
}

// ---------------- NT GEMM: C(M x 128-col tiles) = A(MxK) * B(NxK)^T, BM x 128 tile, BK=64 ----
// Proven r0 structure (m97-ceiling ~916 TF; within-structure levers measured-null r1-r4).
// LDS rows are 128B (full bank wrap): XOR chunk-col with (row&7); 2 lanes/bank = free [m136].
// EPI 0: +bias, bf16 | 1: exp*scale, bf16 + atomic rowsum | 2: /rowsum, bf16 | 3: +bias, fp32
// EPI 5 (r7): fused QKV projection. y-blocks cover all 3072 weight rows of Wc;
//   n0 <  2048 -> Q/K columns, normal bf16 +bias write into QKV.
//   n0 >= 2048 -> V columns, DIRECT-TRANSPOSED write into VT[b][d][s]: MFMA C-layout
//   gives r=0..3 consecutive rows (s-dim) -> pack ushort4 (8B/lane, 32B runs per q4
//   group). b = grow>>12, s = grow&4095 (store never crosses a batch: s0w is 4-aligned,
//   batches 4096-aligned). Replaces the separate V dispatch AND V's QKV round trip.
template <int EPI, int BM>
__global__ __launch_bounds__(256, 2) void gemm_nt(
    const bf16* __restrict__ A, int lda, long sA,
    const bf16* __restrict__ B, int ldb, long sB,
    void* __restrict__ Cout, int ldc, long sC,
    int K, const float* __restrict__ bias,
    float* __restrict__ rowsum, int sL, float scale,
    bf16* __restrict__ vt) {
    constexpr int MI = BM / 32;                 // 16-row fragment blocks per wave (rows)
    __shared__ __align__(16) bf16 As[BM * 64];  // BM=128: 16 KB, BM=64: 8 KB
    __shared__ __align__(16) bf16 Bs[128 * 64]; // 16 KB
    const int tid = threadIdx.x;
    const int lane = tid & 63;
    const int wave = tid >> 6;
    const int bz = blockIdx.z;
    const int m0 = blockIdx.x * BM, n0 = blockIdx.y * 128;
    A += (long)bz * sA;
    B += (long)bz * sB;
    rowsum += (long)bz * sL;

    const int wr = (wave >> 1) * (BM / 2);
    const int wc = (wave & 1) * 64;
    const int fm = lane & 15;
    const int q4 = lane >> 4;
    const int sw = fm & 7;                       // row&7 for all fragment rows
    const int rd0 = ((q4 ^ sw) << 3);            // k-half 0 chunk offset (elements)
    const int rd1 = (((4 + q4) ^ sw) << 3);      // k-half 1 chunk offset

    f32x4 zero = {0.f, 0.f, 0.f, 0.f};
    f32x4 acc[MI][4];
#pragma unroll
    for (int i = 0; i < MI; i++)
#pragma unroll
        for (int j = 0; j < 4; j++) acc[i][j] = zero;

    for (int k0 = 0; k0 < K; k0 += 64) {
        // stage A: BM*8 16B-chunks; LDS slot c is fixed, global chunk-col is XOR-swizzled
#pragma unroll
        for (int t = 0; t < BM / 32; t++) {
            int c = tid + t * 256;
            int row = c >> 3;
            int q = (((c & 7) ^ (row & 7)) << 3);
            gld_lds16(A + (long)(m0 + row) * lda + k0 + q, As + c * 8);
        }
#pragma unroll
        for (int t = 0; t < 4; t++) {
            int c = tid + t * 256;
            int row = c >> 3;
            int q = (((c & 7) ^ (row & 7)) << 3);
            gld_lds16(B + (long)(n0 + row) * ldb + k0 + q, Bs + c * 8);
        }
        __syncthreads();
#pragma unroll
        for (int kh = 0; kh < 2; kh++) {
            const int rdo = kh ? rd1 : rd0;
            bf16x8 af[MI], bfr[4];
#pragma unroll
            for (int i = 0; i < MI; i++)
                af[i] = *(const bf16x8*)(As + (wr + i * 16 + fm) * 64 + rdo);
#pragma unroll
            for (int j = 0; j < 4; j++)
                bfr[j] = *(const bf16x8*)(Bs + (wc + j * 16 + fm) * 64 + rdo);
#pragma unroll
            for (int i = 0; i < MI; i++)
#pragma unroll
                for (int j = 0; j < 4; j++)
                    acc[i][j] = __builtin_amdgcn_mfma_f32_16x16x32_bf16(
                        af[i], bfr[j], acc[i][j], 0, 0, 0);
        }
        __syncthreads();
    }

    // C/D layout: col = lane&15, row = (lane>>4)*4 + reg  [m89/m91]
    if constexpr (EPI == 5) {
        if (n0 >= 2048) {
            // transposed V write into VT[b][d][s]
#pragma unroll
            for (int i = 0; i < MI; i++) {
                const int s0w = m0 + wr + i * 16 + q4 * 4;   // global row (b*4096+s)
                const int b = s0w >> 12, s = s0w & 4095;
#pragma unroll
                for (int j = 0; j < 4; j++) {
                    const int gcol = n0 + wc + j * 16 + fm;  // 2048 + d
                    const float bvv = bias[gcol];
                    union { ushort4 u; bf16 h[4]; } pk;
#pragma unroll
                    for (int r = 0; r < 4; r++)
                        pk.h[r] = __float2bfloat16(acc[i][j][r] + bvv);
                    *(ushort4*)(vt + (long)b * D_ * S_ +
                                (long)(gcol - 2048) * S_ + s) = pk.u;
                }
            }
            return;
        }
    }
    (void)vt;

#pragma unroll
    for (int i = 0; i < MI; i++)
#pragma unroll
        for (int r = 0; r < 4; r++) {
            const int grow = m0 + wr + q4 * 4 + i * 16 + r;
            if constexpr (EPI == 0 || EPI == 5) {
#pragma unroll
                for (int j = 0; j < 4; j++) {
                    int gcol = n0 + wc + j * 16 + fm;
                    ((bf16*)Cout)[(long)bz * sC + (long)grow * ldc + gcol] =
                        __float2bfloat16(acc[i][j][r] + bias[gcol]);
                }
            } else if constexpr (EPI == 1) {
                float s = 0.f;
#pragma unroll
                for (int j = 0; j < 4; j++) {
                    int gcol = n0 + wc + j * 16 + fm;
                    float v = __expf(acc[i][j][r] * scale);
                    bf16 hv = __float2bfloat16(v);
                    ((bf16*)Cout)[(long)bz * sC + (long)grow * ldc + gcol] = hv;
                    s += __bfloat162float(hv);  // sum what we actually stored
                }
                s += __shfl_xor(s, 1, 16);
                s += __shfl_xor(s, 2, 16);
                s += __shfl_xor(s, 4, 16);
                s += __shfl_xor(s, 8, 16);
                if (fm == 0) atomicAdd(rowsum + grow, s);
            } else if constexpr (EPI == 2) {
                float inv = 1.0f / rowsum[grow];
#pragma unroll
                for (int j = 0; j < 4; j++) {
                    int gcol = n0 + wc + j * 16 + fm;
                    ((bf16*)Cout)[(long)bz * sC + (long)grow * ldc + gcol] =
                        __float2bfloat16(acc[i][j][r] * inv);
                }
            } else {
#pragma unroll
                for (int j = 0; j < 4; j++) {
                    int gcol = n0 + wc + j * 16 + fm;
                    ((float*)Cout)[(long)bz * sC + (long)grow * ldc + gcol] =
                        acc[i][j][r] + bias[gcol];
                }
            }
        }
}

extern "C" void kernel_launch(void* const* d_in, const int* in_sizes, int n_in,
                              void* d_out, int out_size, void* d_ws, size_t ws_size,
                              hipStream_t stream) {
    const float* x  = (const float*)d_in[0];
    const float* wq = (const float*)d_in[1];
    const float* bq = (const float*)d_in[2];
    const float* wk = (const float*)d_in[3];
    const float* bk = (const float*)d_in[4];
    const float* wv = (const float*)d_in[5];
    const float* bv = (const float*)d_in[6];
    const float* wo = (const float*)d_in[7];
    const float* bo = (const float*)d_in[8];
    (void)in_sizes; (void)n_in; (void)out_size;

    // base ws carve: 104.07 MiB (proven to fit)
    char* p = (char*)d_ws;
    bf16* Wc  = (bf16*)p;  p += (long)N3_ * D_ * 2;   // 6 MiB
    bf16* Wo  = (bf16*)p;  p += (long)D_ * D_ * 2;    // 2 MiB
    float* bc = (float*)p; p += N3_ * 4;              // 12 KiB
    bf16* QKV = (bf16*)p;  p += (long)BS_ * N3_ * 2;  // 96 MiB; Q cols become At
    float* ls = (float*)p; p += (long)BS_ * 4;        // 64 KiB
    // base end = 109,129,728 bytes

    bf16* xb = (bf16*)d_out;                          // 32 MiB; dead after QKV GEMM

    const size_t base = 109129728UL;
    int tier;
    bf16 *VT, *E;
    if (ws_size >= base + 134217728UL) {
        tier = 2;
        E  = (bf16*)p;                                // 128 MiB in ws
        VT = (bf16*)((char*)d_out + 33554432);        // 32 MiB upper half of d_out
    } else if (ws_size >= base + 33554432UL) {
        tier = 1;
        VT = (bf16*)p;                                // 32 MiB in ws
        E  = (bf16*)d_out;                            // 2 slots x 32 MiB
    } else {
        tier = 0;
        VT = (bf16*)((char*)d_out + 33554432);
        E  = (bf16*)d_out;                            // 1 slot
    }
    // VT is disjoint from xb (lower 32 MiB of d_out) in every tier, so the
    // fused projection GEMM may write VT while reading xb.

    // 1) fused prologue
    prologue<<<dim3(20545), 256, 0, stream>>>(x, wq, wk, wv, wo, bq, bk, bv,
                                              xb, Wc, Wo, bc, ls);

    // 2) fused projections: Q,K -> QKV cols [0,2048); V -> VT transposed
    //    (M=16384, N=3072, K=1024 in ONE dispatch; y>=16 blocks are V)
    gemm_nt<5, 128><<<dim3(BS_ / 128, N3_ / 128, 1), 256, 0, stream>>>(
        xb, D_, 0, Wc, D_, 0, QKV, N3_, 0, D_, bc, ls, 0, 1.f, VT);

    // 3) attention: E = exp(QK^T/32) (+rowsum), At = (E V)/rowsum -> Q region
    if (tier == 2) {
        gemm_nt<1, 128><<<dim3(32, 32, 4), 256, 0, stream>>>(
            QKV, N3_, (long)S_ * N3_, QKV + 1024, N3_, (long)S_ * N3_,
            E, S_, (long)S_ * S_, D_, nullptr, ls, S_, 0.03125f, nullptr);
        gemm_nt<2, 128><<<dim3(32, 8, 4), 256, 0, stream>>>(
            E, S_, (long)S_ * S_, VT, S_, (long)D_ * S_,
            QKV, N3_, (long)S_ * N3_, S_, nullptr, ls, S_, 1.f, nullptr);
    } else if (tier == 1) {
        for (int pr = 0; pr < 2; ++pr) {
            const long qoff = (long)(2 * pr) * S_ * N3_;
            gemm_nt<1, 128><<<dim3(32, 32, 2), 256, 0, stream>>>(
                QKV + qoff, N3_, (long)S_ * N3_,
                QKV + qoff + 1024, N3_, (long)S_ * N3_,
                E, S_, (long)S_ * S_, D_, nullptr, ls + 2 * pr * S_, S_, 0.03125f, nullptr);
            gemm_nt<2, 128><<<dim3(32, 8, 2), 256, 0, stream>>>(
                E, S_, (long)S_ * S_,
                VT + (long)(2 * pr) * D_ * S_, S_, (long)D_ * S_,
                QKV + qoff, N3_, (long)S_ * N3_, S_, nullptr, ls + 2 * pr * S_, S_, 1.f, nullptr);
        }
    } else {
        for (int b = 0; b < B_; ++b) {
            const long qoff = (long)b * S_ * N3_;
            gemm_nt<1, 128><<<dim3(32, 32, 1), 256, 0, stream>>>(
                QKV + qoff, N3_, 0, QKV + qoff + 1024, N3_, 0,
                E, S_, 0, D_, nullptr, ls + b * S_, 0, 0.03125f, nullptr);
            gemm_nt<2, 64><<<dim3(64, 8, 1), 256, 0, stream>>>(
                E, S_, 0, VT + (long)b * D_ * S_, S_, 0,
                QKV + qoff, N3_, 0, S_, nullptr, ls + b * S_, 0, 1.f, nullptr);
        }
    }

    // 5) out = At @ Wo^T + bo -> fp32  (M=16384, N=1024, K=1024; A row stride 3072)
    gemm_nt<3, 128><<<dim3(BS_ / 128, D_ / 128, 1), 256, 0, stream>>>(
        QKV, N3_, 0, Wo, D_, 0, d_out, D_, 0, D_, bo, ls, 0, 1.f, nullptr);
}